// Round 1
// baseline (253.199 us; speedup 1.0000x reference)
//
#include <hip/hip_runtime.h>
#include <math.h>

// B=4, H=256, W=256, 100 iters. Closed-form update (3-pt GH quadrature is
// exact for these degree<=4 integrands; log/NDC terms cancel):
//   dmu  = 2*uw1*mu + uw2*y + sum_edges ew*mu_nb
//   dsg  = 2*uw1*sg + sum_edges ew*rou_edge*sg_nb
//   drou = ew*sg_self*sg_nb        (per owned edge)
// Temporal blocking: T=10 iters/launch, 256 blocks (1/CU), double-buffered
// LDS, 1 barrier/iter.
// Round 9: concurrency restructure. The iter phase ran at ~2x its DS/VALU
// throughput floor -> latency/barrier-bound with only 676/1024 threads
// (10.6/16 waves) active. Switch 4 rows/thread -> 3 rows/thread:
// tile 54x52 (halo 11 rows / 10 cols), NRG=18, ACTIVE=936 (91%), 14.6
// active waves. Register state drops 25% (st/v/k1/k2 x3 not x4) -> slack
// under the 128-VGPR cap of __launch_bounds__(1024,4). k2.x for k>0 comes
// from k1[k-1].z (register) instead of LDS. Global bytes +4% (2 extra halo
// rows); DS instr/px ~flat (11 per 3 px vs 14 per 4).
#define NPIX  262144
#define NEDGE 524288
#define ITERS 100
#define T     10
#define TILE_R 54           // 32 + 11 + 11 (1 spare garbage row)
#define TILE_C 52           // 32 + 2*T
#define TS    53            // padded LDS row stride (float4 units)
#define RPT   3             // rows per thread
#define NRG   18            // rowgroups of 3 rows: 18*3 = 54 exact
#define ACTIVE (TILE_C*NRG) // 936 active threads of 1024
#define HALO_R 11

__device__ __forceinline__ float clampf(float x, float lo, float hi) {
    return fminf(fmaxf(x, lo), hi);
}

// State float4 {mu, sigma, rou0(down-edge), rou1(right-edge)}.
// c1 = {2*uw1, uw2*y, ew0, ew1}.
__global__ __launch_bounds__(1024, 4) void tile_kernel(
    const float4* __restrict__ stI, const float4* __restrict__ vI,
    float4* __restrict__ stO, float4* __restrict__ vO,
    const float4* __restrict__ c1,
    float* __restrict__ mu_out,   // non-null on last launch (st/v not stored)
    int first)                    // launch 0: v := 0, vI not read
{
    __shared__ float4 buf[2][TILE_R*TS];   // 91.6 KB

    int tid = threadIdx.x;
    int rg  = tid / TILE_C;
    int col = tid - rg*TILE_C;
    bool act = (tid < ACTIVE);
    int bz = blockIdx.z;
    int h0 = blockIdx.y * 32;
    int w0 = blockIdx.x * 32;
    int w  = (w0 + col - T) & 255;

    float4 st[RPT], v[RPT], k1[RPT];
    float2 k2[RPT];
    int gidx[RPT];

    // ---- load tile: st -> LDS buf0 + regs; c1 -> regs; ew pair -> buf1 ----
    float2* ews = (float2*)&buf[1][0];   // staging view, overwritten by iter 0
    if (act) {
#pragma unroll
        for (int k = 0; k < RPT; ++k) {
            int r = RPT*rg + k;
            int h = (h0 + r - HALO_R) & 255;
            int g = (bz << 16) | (h << 8) | w;
            gidx[k] = g;
            float4 s = stI[g];
            st[k] = s;
            buf[0][r*TS + col] = s;
            float4 K = c1[g];
            k1[k] = K;
            ews[r*TS + col] = make_float2(K.z, K.w);   // {ew0, ew1}
            v[k] = first ? make_float4(0.f, 0.f, 0.f, 0.f) : vI[g];
        }
    }
    __syncthreads();

    // gather neighbor ew: k2 = {ew0 of up-nb, ew1 of left-nb}. Up-nb ew0 for
    // k>0 is k1[k-1].z (register); only k=0 needs the LDS staging plane.
    // Clamped at tile edge -> finite garbage; edge px are garbage-region.
    int cl = (col == 0)          ? 0          : col-1;
    int cr = (col == TILE_C-1)   ? TILE_C-1   : col+1;
    if (act) {
        int r0 = RPT*rg;
        int ru = (r0 == 0) ? 0 : r0-1;
        k2[0] = make_float2(ews[ru*TS + col].x, ews[r0*TS + cl].y);
#pragma unroll
        for (int k = 1; k < RPT; ++k) {
            int r = r0 + k;
            k2[k] = make_float2(k1[k-1].z, ews[r*TS + cl].y);
        }
    }
    __syncthreads();   // k2 reads done before iter-0 writes buf1

    // ---- T fused Jacobi iterations, one barrier each ----
    for (int s = 0; s < T; ++s) {
        const float4* __restrict__ cur = buf[s & 1];
        float4*       __restrict__ nxt = buf[(s & 1) ^ 1];
        if (act) {
            int r0 = RPT*rg;
            float4 ns[RPT];
            float4 up0 = cur[((rg == 0)     ? 0          : (r0-1))*TS + col];
            float4 dnL = cur[((rg == NRG-1) ? (TILE_R-1) : (r0+RPT))*TS + col];
#pragma unroll
            for (int k = 0; k < RPT; ++k) {
                int r = r0 + k;
                float4 lf = cur[r*TS + cl];
                float4 rt = cur[r*TS + cr];
                float4 up = (k == 0)     ? up0 : st[k-1];
                float4 dn = (k == RPT-1) ? dnL : st[k+1];
                float4 S  = st[k];
                float4 K  = k1[k];
                float2 K2 = k2[k];
                float dmu = K.x*S.x + K.y + K.z*dn.x + K.w*rt.x
                          + K2.x*up.x + K2.y*lf.x;
                float dsg = K.x*S.y + K.z*S.z*dn.y + K.w*S.w*rt.y
                          + K2.x*up.z*up.y + K2.y*lf.w*lf.y;
                float dr0 = K.z*S.y*dn.y;
                float dr1 = K.w*S.y*rt.y;
                float4 V = v[k];
                V.x = 0.7f*V.x + 0.01f*dmu;
                V.y = 0.7f*V.y + 0.01f*dsg;
                V.z = 0.7f*V.z + 0.01f*dr0;
                V.w = 0.7f*V.w + 0.01f*dr1;
                v[k] = V;
                float4 o;
                o.x = clampf(S.x + V.x, 0.f, 63.f);
                o.y = clampf(S.y + V.y, 0.001f, 50.f);
                o.z = clampf(S.z + V.z, -0.99f, 0.99f);
                o.w = clampf(S.w + V.w, -0.99f, 0.99f);
                ns[k] = o;
            }
#pragma unroll
            for (int k = 0; k < RPT; ++k) {
                st[k] = ns[k];
                nxt[(r0 + k)*TS + col] = ns[k];
            }
        }
        __syncthreads();   // all reads of cur done AND nxt fully written
    }

    // ---- store interior (rows [HALO_R, HALO_R+32), cols [T, T+32)) ----
    if (act && col >= T && col < T+32) {
#pragma unroll
        for (int k = 0; k < RPT; ++k) {
            int r = RPT*rg + k;
            if (r >= HALO_R && r < HALO_R+32) {
                int g = gidx[k];
                if (mu_out) {
                    mu_out[g] = st[k].x;     // final launch: only mu needed
                } else {
                    stO[g] = st[k];
                    vO[g]  = v[k];
                }
            }
        }
    }
}

// ---- global max(edge_weight); gmax pre-zeroed via hipMemsetAsync ----
// (0u is the order-preserving encoding of the most-negative float)
__global__ void reduce_max_kernel(const float* __restrict__ ew, unsigned int* gmax) {
    int i = blockIdx.x*blockDim.x + threadIdx.x;
    float m = -INFINITY;
    for (; i < NEDGE; i += gridDim.x*blockDim.x) m = fmaxf(m, ew[i]);
#pragma unroll
    for (int off = 32; off > 0; off >>= 1)
        m = fmaxf(m, __shfl_down(m, off, 64));
    if ((threadIdx.x & 63) == 0) {
        unsigned u = __float_as_uint(m);
        unsigned key = (u & 0x80000000u) ? ~u : (u | 0x80000000u);
        atomicMax(gmax, key);
    }
}

// init state + invariant coefficient plane (no v plane, no c2 plane)
__global__ __launch_bounds__(256) void init_state_kernel(
    const float*  __restrict__ y,
    const float2* __restrict__ ew,
    const float2* __restrict__ uw,
    const unsigned int* __restrict__ gmax_enc,
    float4* stA, float4* c1)
{
    int idx = blockIdx.x*256 + threadIdx.x;

    unsigned key = *gmax_enc;
    unsigned u = (key & 0x80000000u) ? (key ^ 0x80000000u) : ~key;
    float gmax = __uint_as_float(u);
    float inv_denom = 1.f / (gmax*1.01f + 1.f);   // one-time, IEEE div fine

    float2 e   = ew[idx];
    float2 uwv = uw[idx];
    float  yv  = y[idx];
    float4 st;
    st.x = yv;
    st.y = 1.f;
    st.z = e.x * inv_denom;
    st.w = e.y * inv_denom;
    stA[idx] = st;
    c1[idx]  = make_float4(2.f*uwv.x, uwv.y*yv, e.x, e.y);
}

extern "C" void kernel_launch(void* const* d_in, const int* in_sizes, int n_in,
                              void* d_out, int out_size, void* d_ws, size_t ws_size,
                              hipStream_t stream) {
    const float* y  = (const float*)d_in[0];
    const float* ew = (const float*)d_in[1];
    const float* uw = (const float*)d_in[2];
    float* out = (float*)d_out;
    const int N = NPIX;

    // workspace: stA, stB, vA, vB, c1 (float4 planes) + 1 uint (~21 MB)
    float4* stA = (float4*)d_ws;
    float4* stB = stA + N;
    float4* vA  = stB + N;
    float4* vB  = vA + N;
    float4* c1  = vB + N;
    unsigned int* gmax = (unsigned int*)(c1 + N);

    hipMemsetAsync(gmax, 0, sizeof(unsigned int), stream);
    hipLaunchKernelGGL(reduce_max_kernel, dim3(512), dim3(256), 0, stream, ew, gmax);
    hipLaunchKernelGGL(init_state_kernel, dim3(N/256), dim3(256), 0, stream,
                       y, (const float2*)ew, (const float2*)uw, gmax,
                       stA, c1);

    float4 *stI = stA, *stO = stB, *vI = vA, *vO = vB;
    const int NLAUNCH = ITERS / T;   // 10
    for (int l = 0; l < NLAUNCH; ++l) {
        float* mo = (l == NLAUNCH-1) ? out : nullptr;
        hipLaunchKernelGGL(tile_kernel, dim3(8, 8, 4), dim3(1024), 0, stream,
                           stI, vI, stO, vO, c1, mo, (l == 0) ? 1 : 0);
        float4* t;
        t = stI; stI = stO; stO = t;
        t = vI;  vI  = vO;  vO  = t;
    }
}

// Round 2
// 239.224 us; speedup vs baseline: 1.0584x; 1.0584x over previous
//
#include <hip/hip_runtime.h>
#include <math.h>

// B=4, H=256, W=256, 100 iters. Closed-form update (3-pt GH quadrature is
// exact for these degree<=4 integrands; log/NDC terms cancel):
//   dmu  = 2*uw1*mu + uw2*y + sum_edges ew*mu_nb
//   dsg  = 2*uw1*sg + sum_edges ew*rou_edge*sg_nb
//   drou = ew*sg_self*sg_nb        (per owned edge)
// Temporal blocking: T=10 iters/launch, 256 blocks (1/CU), double-buffered
// LDS, 1 barrier/iter. 3 rows/thread (NRG=18, ACTIVE=936, 14.6 waves).
// Round 10: shrinking active region. Only rows [2+s, 51-s] of the tile can
// still influence the stored interior at step s; gate the iteration body per
// rowgroup (rgLo=ceil(s/3), rgHi=(51-s)/3). 144 vs 180 rowgroup-iters
// (-20% DS/VALU issue; ~-16% at wave granularity). Rows outside the gate go
// stale in LDS, but the garbage front advances 1 row/step exactly behind the
// shrinking validity front (same argument as edge-clamp garbage); stored
// rows 11..42 = rowgroups 3..14 stay active through s=9. All values stay
// finite (clamped states x finite coeffs), so no NaN/Inf poisoning.
#define NPIX  262144
#define NEDGE 524288
#define ITERS 100
#define T     10
#define TILE_R 54           // 32 + 11 + 11 (1 spare garbage row)
#define TILE_C 52           // 32 + 2*T
#define TS    53            // padded LDS row stride (float4 units)
#define RPT   3             // rows per thread
#define NRG   18            // rowgroups of 3 rows: 18*3 = 54 exact
#define ACTIVE (TILE_C*NRG) // 936 active threads of 1024
#define HALO_R 11

__device__ __forceinline__ float clampf(float x, float lo, float hi) {
    return fminf(fmaxf(x, lo), hi);
}

// State float4 {mu, sigma, rou0(down-edge), rou1(right-edge)}.
// c1 = {2*uw1, uw2*y, ew0, ew1}.
__global__ __launch_bounds__(1024, 4) void tile_kernel(
    const float4* __restrict__ stI, const float4* __restrict__ vI,
    float4* __restrict__ stO, float4* __restrict__ vO,
    const float4* __restrict__ c1,
    float* __restrict__ mu_out,   // non-null on last launch (st/v not stored)
    int first)                    // launch 0: v := 0, vI not read
{
    __shared__ float4 buf[2][TILE_R*TS];   // 91.6 KB

    int tid = threadIdx.x;
    int rg  = tid / TILE_C;
    int col = tid - rg*TILE_C;
    bool act = (tid < ACTIVE);
    int bz = blockIdx.z;
    int h0 = blockIdx.y * 32;
    int w0 = blockIdx.x * 32;
    int w  = (w0 + col - T) & 255;

    float4 st[RPT], v[RPT], k1[RPT];
    float2 k2[RPT];
    int gidx[RPT];

    // ---- load tile: st -> LDS buf0 + regs; c1 -> regs; ew pair -> buf1 ----
    float2* ews = (float2*)&buf[1][0];   // staging view, overwritten by iter 0
    if (act) {
#pragma unroll
        for (int k = 0; k < RPT; ++k) {
            int r = RPT*rg + k;
            int h = (h0 + r - HALO_R) & 255;
            int g = (bz << 16) | (h << 8) | w;
            gidx[k] = g;
            float4 s = stI[g];
            st[k] = s;
            buf[0][r*TS + col] = s;
            float4 K = c1[g];
            k1[k] = K;
            ews[r*TS + col] = make_float2(K.z, K.w);   // {ew0, ew1}
            v[k] = first ? make_float4(0.f, 0.f, 0.f, 0.f) : vI[g];
        }
    }
    __syncthreads();

    // gather neighbor ew: k2 = {ew0 of up-nb, ew1 of left-nb}. Up-nb ew0 for
    // k>0 is k1[k-1].z (register); only k=0 needs the LDS staging plane.
    // Clamped at tile edge -> finite garbage; edge px are garbage-region.
    int cl = (col == 0)          ? 0          : col-1;
    int cr = (col == TILE_C-1)   ? TILE_C-1   : col+1;
    if (act) {
        int r0 = RPT*rg;
        int ru = (r0 == 0) ? 0 : r0-1;
        k2[0] = make_float2(ews[ru*TS + col].x, ews[r0*TS + cl].y);
#pragma unroll
        for (int k = 1; k < RPT; ++k) {
            int r = r0 + k;
            k2[k] = make_float2(k1[k-1].z, ews[r*TS + cl].y);
        }
    }
    __syncthreads();   // k2 reads done before iter-0 writes buf1

    // ---- T fused Jacobi iterations, one barrier each, shrinking gate ----
    for (int s = 0; s < T; ++s) {
        const float4* __restrict__ cur = buf[s & 1];
        float4*       __restrict__ nxt = buf[(s & 1) ^ 1];
        int rgLo = (s + 2) / 3;      // ceil(s/3)
        int rgHi = (51 - s) / 3;
        if (act && rg >= rgLo && rg <= rgHi) {
            int r0 = RPT*rg;
            float4 ns[RPT];
            float4 up0 = cur[((rg == 0)     ? 0          : (r0-1))*TS + col];
            float4 dnL = cur[((rg == NRG-1) ? (TILE_R-1) : (r0+RPT))*TS + col];
#pragma unroll
            for (int k = 0; k < RPT; ++k) {
                int r = r0 + k;
                float4 lf = cur[r*TS + cl];
                float4 rt = cur[r*TS + cr];
                float4 up = (k == 0)     ? up0 : st[k-1];
                float4 dn = (k == RPT-1) ? dnL : st[k+1];
                float4 S  = st[k];
                float4 K  = k1[k];
                float2 K2 = k2[k];
                float dmu = K.x*S.x + K.y + K.z*dn.x + K.w*rt.x
                          + K2.x*up.x + K2.y*lf.x;
                float dsg = K.x*S.y + K.z*S.z*dn.y + K.w*S.w*rt.y
                          + K2.x*up.z*up.y + K2.y*lf.w*lf.y;
                float dr0 = K.z*S.y*dn.y;
                float dr1 = K.w*S.y*rt.y;
                float4 V = v[k];
                V.x = 0.7f*V.x + 0.01f*dmu;
                V.y = 0.7f*V.y + 0.01f*dsg;
                V.z = 0.7f*V.z + 0.01f*dr0;
                V.w = 0.7f*V.w + 0.01f*dr1;
                v[k] = V;
                float4 o;
                o.x = clampf(S.x + V.x, 0.f, 63.f);
                o.y = clampf(S.y + V.y, 0.001f, 50.f);
                o.z = clampf(S.z + V.z, -0.99f, 0.99f);
                o.w = clampf(S.w + V.w, -0.99f, 0.99f);
                ns[k] = o;
            }
#pragma unroll
            for (int k = 0; k < RPT; ++k) {
                st[k] = ns[k];
                nxt[(r0 + k)*TS + col] = ns[k];
            }
        }
        __syncthreads();   // all reads of cur done AND nxt fully written
    }

    // ---- store interior (rows [HALO_R, HALO_R+32), cols [T, T+32)) ----
    if (act && col >= T && col < T+32) {
#pragma unroll
        for (int k = 0; k < RPT; ++k) {
            int r = RPT*rg + k;
            if (r >= HALO_R && r < HALO_R+32) {
                int g = gidx[k];
                if (mu_out) {
                    mu_out[g] = st[k].x;     // final launch: only mu needed
                } else {
                    stO[g] = st[k];
                    vO[g]  = v[k];
                }
            }
        }
    }
}

// ---- global max(edge_weight); gmax pre-zeroed via hipMemsetAsync ----
// (0u is the order-preserving encoding of the most-negative float)
__global__ void reduce_max_kernel(const float* __restrict__ ew, unsigned int* gmax) {
    int i = blockIdx.x*blockDim.x + threadIdx.x;
    float m = -INFINITY;
    for (; i < NEDGE; i += gridDim.x*blockDim.x) m = fmaxf(m, ew[i]);
#pragma unroll
    for (int off = 32; off > 0; off >>= 1)
        m = fmaxf(m, __shfl_down(m, off, 64));
    if ((threadIdx.x & 63) == 0) {
        unsigned u = __float_as_uint(m);
        unsigned key = (u & 0x80000000u) ? ~u : (u | 0x80000000u);
        atomicMax(gmax, key);
    }
}

// init state + invariant coefficient plane (no v plane, no c2 plane)
__global__ __launch_bounds__(256) void init_state_kernel(
    const float*  __restrict__ y,
    const float2* __restrict__ ew,
    const float2* __restrict__ uw,
    const unsigned int* __restrict__ gmax_enc,
    float4* stA, float4* c1)
{
    int idx = blockIdx.x*256 + threadIdx.x;

    unsigned key = *gmax_enc;
    unsigned u = (key & 0x80000000u) ? (key ^ 0x80000000u) : ~key;
    float gmax = __uint_as_float(u);
    float inv_denom = 1.f / (gmax*1.01f + 1.f);   // one-time, IEEE div fine

    float2 e   = ew[idx];
    float2 uwv = uw[idx];
    float  yv  = y[idx];
    float4 st;
    st.x = yv;
    st.y = 1.f;
    st.z = e.x * inv_denom;
    st.w = e.y * inv_denom;
    stA[idx] = st;
    c1[idx]  = make_float4(2.f*uwv.x, uwv.y*yv, e.x, e.y);
}

extern "C" void kernel_launch(void* const* d_in, const int* in_sizes, int n_in,
                              void* d_out, int out_size, void* d_ws, size_t ws_size,
                              hipStream_t stream) {
    const float* y  = (const float*)d_in[0];
    const float* ew = (const float*)d_in[1];
    const float* uw = (const float*)d_in[2];
    float* out = (float*)d_out;
    const int N = NPIX;

    // workspace: stA, stB, vA, vB, c1 (float4 planes) + 1 uint (~21 MB)
    float4* stA = (float4*)d_ws;
    float4* stB = stA + N;
    float4* vA  = stB + N;
    float4* vB  = vA + N;
    float4* c1  = vB + N;
    unsigned int* gmax = (unsigned int*)(c1 + N);

    hipMemsetAsync(gmax, 0, sizeof(unsigned int), stream);
    hipLaunchKernelGGL(reduce_max_kernel, dim3(512), dim3(256), 0, stream, ew, gmax);
    hipLaunchKernelGGL(init_state_kernel, dim3(N/256), dim3(256), 0, stream,
                       y, (const float2*)ew, (const float2*)uw, gmax,
                       stA, c1);

    float4 *stI = stA, *stO = stB, *vI = vA, *vO = vB;
    const int NLAUNCH = ITERS / T;   // 10
    for (int l = 0; l < NLAUNCH; ++l) {
        float* mo = (l == NLAUNCH-1) ? out : nullptr;
        hipLaunchKernelGGL(tile_kernel, dim3(8, 8, 4), dim3(1024), 0, stream,
                           stI, vI, stO, vO, c1, mo, (l == 0) ? 1 : 0);
        float4* t;
        t = stI; stI = stO; stO = t;
        t = vI;  vI  = vO;  vO  = t;
    }
}